// Round 4
// baseline (494.433 us; speedup 1.0000x reference)
//
#include <hip/hip_runtime.h>
#include <hip/hip_bf16.h>

// Problem constants
#define NB 16      // batch
#define NN 1024    // nodes
#define CIN 16
#define TT 36
#define KK 3
#define COUT 64
#define CT 576     // CIN*TT
#define KB 48      // KK*NB

typedef __attribute__((ext_vector_type(8))) short bf16x8;
typedef __attribute__((ext_vector_type(4))) float f32x4;

__device__ __forceinline__ unsigned short f2bf(float f) {
    union { float f; unsigned int u; } v; v.f = f;
    unsigned int r = v.u + 0x7FFF + ((v.u >> 16) & 1);
    return (unsigned short)(r >> 16);
}

// -------- prep_a: At[l][n - n_base][m] = bf16(cheb[k][m][n] * SAt[b][m][n]) --------
// One block per (k, 64x64 tile position); loops b=0..15 with the cheb tile pinned
// in registers; next-b sat load issued before the barrier (overlaps write-out).
__global__ __launch_bounds__(256) void prep_a(const float* __restrict__ cheb,
                                              const float* __restrict__ sat,
                                              ushort* __restrict__ At,
                                              int n_base, int rows) {
    __shared__ ushort tile[64][68];
    const int ntiles = rows >> 6;
    const int k = blockIdx.y;
    const int n0 = n_base + (blockIdx.x % ntiles) * 64;
    const int m0 = (blockIdx.x / ntiles) * 64;
    const int tid = threadIdx.x;

    size_t goff[4];
    float4 cv[4], sv[4];
#pragma unroll
    for (int i = 0; i < 4; ++i) {
        int f = i * 256 + tid;
        goff[i] = (size_t)(m0 + (f >> 4)) * NN + n0 + ((f & 15) << 2);
        cv[i] = *(const float4*)(cheb + (size_t)k * NN * NN + goff[i]);
        sv[i] = *(const float4*)(sat + goff[i]);      // b = 0
    }
    for (int b = 0; b < 16; ++b) {
#pragma unroll
        for (int i = 0; i < 4; ++i) {
            int f = i * 256 + tid;
            ushort4 u;
            u.x = f2bf(cv[i].x * sv[i].x); u.y = f2bf(cv[i].y * sv[i].y);
            u.z = f2bf(cv[i].z * sv[i].z); u.w = f2bf(cv[i].w * sv[i].w);
            *(ushort4*)&tile[f >> 4][(f & 15) << 2] = u;
        }
        if (b < 15) {
            const float* sa = sat + (size_t)(b + 1) * NN * NN;
#pragma unroll
            for (int i = 0; i < 4; ++i) sv[i] = *(const float4*)(sa + goff[i]);
        }
        __syncthreads();
        ushort* outp = At + (size_t)(k * 16 + b) * rows * NN;
#pragma unroll
        for (int i = 0; i < 4; ++i) {
            int f = i * 256 + tid;
            int n = f >> 4, m4 = (f & 15) << 2;
            ushort4 u;
            u.x = tile[m4 + 0][n]; u.y = tile[m4 + 1][n];
            u.z = tile[m4 + 2][n]; u.w = tile[m4 + 3][n];
            *(ushort4*)(outp + (size_t)(n0 - n_base + n) * NN + m0 + m4) = u;
        }
        __syncthreads();   // tile reused next b-iteration
    }
}

// -------- prep_x: Xt[b][ct'][m] = bf16(x[b][m][c][t]), ct' = t*16 + c --------
__global__ __launch_bounds__(256) void prep_x(const float* __restrict__ x,
                                              ushort* __restrict__ Xt) {
    __shared__ ushort tile[64][68];
    const int b = blockIdx.y;
    const int m0 = (blockIdx.x & 15) * 64;
    const int c0 = (blockIdx.x >> 4) * 64;
    const int tid = threadIdx.x;
    const float* xb = x + (size_t)b * NN * CT;
#pragma unroll
    for (int i = 0; i < 4; ++i) {
        int f = i * 256 + tid;
        int mr = f >> 4, c4 = (f & 15) << 2;
        float4 v = *(const float4*)(xb + (size_t)(m0 + mr) * CT + c0 + c4);
        ushort4 u;
        u.x = f2bf(v.x); u.y = f2bf(v.y); u.z = f2bf(v.z); u.w = f2bf(v.w);
        *(ushort4*)&tile[mr][c4] = u;
    }
    __syncthreads();
    ushort* outp = Xt + (size_t)b * CT * NN;
#pragma unroll
    for (int i = 0; i < 4; ++i) {
        int f = i * 256 + tid;
        int n = f >> 4, m4 = (f & 15) << 2;
        int ctlin = c0 + n;                     // = c*36 + t
        int c = ctlin / 36, t = ctlin - 36 * c;
        int ctp = t * 16 + c;                   // t-major permuted row
        ushort4 u;
        u.x = tile[m4 + 0][n]; u.y = tile[m4 + 1][n];
        u.z = tile[m4 + 2][n]; u.w = tile[m4 + 3][n];
        *(ushort4*)(outp + (size_t)ctp * NN + m0 + m4) = u;
    }
}

// -------- gemm1f: FUSED  out[b,n,o,t] = relu(sum_kc theta[kc,o] * rhs[kc,n,t]) ----
// where rhs[k*16+c, n, t] = sum_m At[k*16+b][n][m] * Xt[b][t*16+c][m].
// R4: (a) revert to the verified R2 2-buffer counted-vmcnt ladder (R3's 3-buffer
// regressed: FETCH +10MB, dur +10us); (b) fuse k=0..2 into one block (BM 128->64,
// acc[3][2][3]) -- B-frags shared across k raise MFMA:LDS ratio 1.71->2.0 and cut
// total staging 737->590MB; (c) fuse the theta contraction as an epilogue:
// per-wave-local LDS restage of acc as [n][kc] bf16 (same XOR involution), theta
// in zero-padded LDS [o][72], 48 MFMA/wave, ReLU + direct store. rhs2 workspace
// and the apply kernel are DELETED (saves 113MB HBM + a dispatch).
// Grid 48x16 = 768 = exactly 3 blocks/CU. XCD: flat = x + 48y, 48y%8==0 ->
// XCD = x%8; A-sharers (same nt, 3 ctt) at x, x+16, x+32 -> same XCD L2.
// kc-pad 48..63: rstage holds stale finite bf16; thT rows there are 0.0 -> 0.
__global__ __launch_bounds__(512) void gemm1f(const ushort* __restrict__ At,
                                              const ushort* __restrict__ Xt,
                                              const float* __restrict__ theta,
                                              float* __restrict__ out,
                                              int nsplit, int n_base, int rows) {
    __shared__ ushort lds[2 * 384 * 64];   // 98,304 B: 2 x [A0|A1|A2 (64x64) | B (192x64)]
    __shared__ ushort thT[64 * 72];        // 9,216 B: [o][kc] pad-stride 72, kc>=48 = 0
    const int tid = threadIdx.x;
    const int b = blockIdx.y;
    const int ntiles = rows >> 6;
    const int nt = blockIdx.x % ntiles;
    const int ctt = blockIdx.x / ntiles;
    const int nloc0 = nt * 64;
    const int ct0 = ctt * 192;
    const int atrows = nsplit ? rows : NN;

    // theta -> LDS (read in epilogue only; lgkm drained long before by K-loop)
    for (int f = tid; f < 64 * 64; f += 512) {
        int o = f >> 6, kc = f & 63;
        thT[o * 72 + kc] = f2bf((kc < 48) ? theta[kc * 64 + o] : 0.f);
    }

    // staging: thread -> (row = tid>>3, chunk = tid&7), 16B slots, source
    // chunk pre-swizzled c ^ (row&7); LDS dest LINEAR (rule #21 both-sides).
    const int srow = tid >> 3, schunk = tid & 7;
    const int swz = schunk ^ (srow & 7);
    const ushort* a_src[3];
#pragma unroll
    for (int k = 0; k < 3; ++k)
        a_src[k] = At + ((size_t)(k * 16 + b) * atrows + nloc0 + srow) * NN + swz * 8;
    const ushort* b_src = Xt + (size_t)b * CT * NN + (size_t)(ct0 + srow) * NN + swz * 8;

    auto STAGE = [&](int kt, int p) {
        const int mk = kt * 64;
        ushort* base = lds + p * (384 * 64);
#pragma unroll
        for (int k = 0; k < 3; ++k)        // A_k: 64 rows x 8 chunks = 512 slots
            __builtin_amdgcn_global_load_lds(
                (const __attribute__((address_space(1))) void*)(a_src[k] + mk),
                (__attribute__((address_space(3))) void*)(base + k * 4096 + tid * 8), 16, 0, 0);
#pragma unroll
        for (int i = 0; i < 3; ++i)        // B: 192 rows x 8 chunks
            __builtin_amdgcn_global_load_lds(
                (const __attribute__((address_space(1))) void*)(b_src + (size_t)i * 64 * NN + mk),
                (__attribute__((address_space(3))) void*)(base + 3 * 4096 + (tid + i * 512) * 8), 16, 0, 0);
    };

    const int w = tid >> 6, lane = tid & 63;
    const int wr = w >> 2, wc = w & 3;            // 2 x 4 wave grid: 32n x 48ct
    const int lrow = lane & 15, quad = lane >> 4;
    const int s3 = lrow & 7;
    f32x4 acc[3][2][3] = {};                      // [k][mi(n)][ni(ct)]

    STAGE(0, 0);                                  //  6 in flight
    STAGE(1, 1);                                  // 12 in flight
    asm volatile("s_waitcnt vmcnt(6)\n\ts_barrier" ::: "memory");   // tile 0 ready

    for (int kt = 0; kt < 16; ++kt) {
        const int p = kt & 1;
        const ushort* bufA = lds + p * (384 * 64);
        const ushort* bufB = bufA + 3 * 4096;
#pragma unroll
        for (int kp = 0; kp < 2; ++kp) {
            const int koff = (((kp * 4 + quad) ^ s3) << 3);   // swizzled k-chunk
            bf16x8 af[3][2], bfr[3];
#pragma unroll
            for (int k = 0; k < 3; ++k)
#pragma unroll
                for (int mi = 0; mi < 2; ++mi)
                    af[k][mi] = *(const bf16x8*)&bufA[k * 4096 + (wr * 32 + mi * 16 + lrow) * 64 + koff];
#pragma unroll
            for (int ni = 0; ni < 3; ++ni)
                bfr[ni] = *(const bf16x8*)&bufB[(wc * 48 + ni * 16 + lrow) * 64 + koff];
            __builtin_amdgcn_s_setprio(1);
#pragma unroll
            for (int k = 0; k < 3; ++k)
#pragma unroll
                for (int mi = 0; mi < 2; ++mi)
#pragma unroll
                    for (int ni = 0; ni < 3; ++ni)
                        acc[k][mi][ni] = __builtin_amdgcn_mfma_f32_16x16x32_bf16(
                            af[k][mi], bfr[ni], acc[k][mi][ni], 0, 0, 0);
            __builtin_amdgcn_s_setprio(0);
        }
        asm volatile("s_barrier" ::: "memory");   // all waves done reading buf p
        if (kt + 2 < 16) {
            STAGE(kt + 2, p);                     // refill freed buf; 12 in flight
            asm volatile("s_waitcnt vmcnt(6)\n\ts_barrier" ::: "memory");
        } else if (kt + 1 < 16) {
            asm volatile("s_waitcnt vmcnt(0)\n\ts_barrier" ::: "memory");
        }
    }
    // trailing s_barrier above: all waves past their LDS reads -> safe to reuse.

    // ---- epilogue: wave-local restage [ni][n(32)][kc(64)], XOR-swizzled chunks ----
    ushort* rst = lds + w * 6144;                 // 12,288 B per wave, 8 waves = 98,304
#pragma unroll
    for (int k = 0; k < 3; ++k) {
        const int chunk = k * 2 + (lrow >> 3);    // kc = k*16 + lrow -> chunk, kc&7 = s3
#pragma unroll
        for (int mi = 0; mi < 2; ++mi)
#pragma unroll
            for (int ni = 0; ni < 3; ++ni)
#pragma unroll
                for (int r = 0; r < 4; ++r) {
                    int nrow = mi * 16 + quad * 4 + r;
                    rst[ni * 2048 + nrow * 64 + ((chunk ^ (nrow & 7)) << 3) + s3] =
                        f2bf(acc[k][mi][ni][r]);
                }
    }
    bf16x8 a_th[4][2];                            // theta A-frags: row o = of*16+lrow
#pragma unroll
    for (int of = 0; of < 4; ++of)
#pragma unroll
        for (int ks = 0; ks < 2; ++ks)
            a_th[of][ks] = *(const bf16x8*)&thT[(of * 16 + lrow) * 72 + ks * 32 + quad * 8];

    const int n_g0 = n_base + nloc0 + wr * 32 + lrow;   // D col = lane&15 = n-frag col
    const int t_g0 = ctt * 12 + wc * 3;
    float* ob = out + (size_t)b * NN * (COUT * TT);
#pragma unroll
    for (int ni = 0; ni < 3; ++ni)
#pragma unroll
        for (int nf = 0; nf < 2; ++nf) {
            f32x4 o4[4] = {};
#pragma unroll
            for (int ks = 0; ks < 2; ++ks) {
                // B-frag: col = lrow (n), k-elems = ks*32 + quad*8 + j; nrow&7 == s3
                bf16x8 bfr = *(const bf16x8*)&rst[ni * 2048 + (nf * 16 + lrow) * 64 +
                                                 (((ks * 4 + quad) ^ s3) << 3)];
#pragma unroll
                for (int of = 0; of < 4; ++of)
                    o4[of] = __builtin_amdgcn_mfma_f32_16x16x32_bf16(
                        a_th[of][ks], bfr, o4[of], 0, 0, 0);
            }
            size_t nb2 = (size_t)(n_g0 + nf * 16) * (COUT * TT);
#pragma unroll
            for (int of = 0; of < 4; ++of)
#pragma unroll
                for (int r = 0; r < 4; ++r) {
                    int o = of * 16 + quad * 4 + r;
                    ob[nb2 + (size_t)o * TT + t_g0 + ni] = fmaxf(o4[of][r], 0.f);
                }
        }
}

// -------- naive fallback: zero workspace, fully fused --------
__global__ __launch_bounds__(256) void naive_fused(const float* __restrict__ x,
                                                   const float* __restrict__ sat,
                                                   const float* __restrict__ cheb,
                                                   const float* __restrict__ theta,
                                                   float* __restrict__ out) {
    __shared__ float wgt[3][1024];
    __shared__ float rs[3][576];
    const int tid = threadIdx.x;
    const int n = blockIdx.x, b = blockIdx.y;
    for (int f = tid; f < 3 * 1024; f += 256) {
        int k = f >> 10, m = f & 1023;
        wgt[k][m] = cheb[(size_t)k * NN * NN + (size_t)m * NN + n] *
                    sat[(size_t)b * NN * NN + (size_t)m * NN + n];
    }
    __syncthreads();
    float a0[3] = {}, a1[3] = {}, a2[3] = {};
    const float* xb = x + (size_t)b * NN * CT;
    for (int m = 0; m < 1024; ++m) {
        const float* xr = xb + (size_t)m * CT;
        float x0 = xr[tid];
        float x1 = xr[256 + tid];
        float x2 = (tid < 64) ? xr[512 + tid] : 0.f;
#pragma unroll
        for (int k = 0; k < 3; ++k) {
            float wm = wgt[k][m];
            a0[k] += wm * x0; a1[k] += wm * x1; a2[k] += wm * x2;
        }
    }
#pragma unroll
    for (int k = 0; k < 3; ++k) {
        rs[k][tid] = a0[k];
        rs[k][256 + tid] = a1[k];
        if (tid < 64) rs[k][512 + tid] = a2[k];
    }
    __syncthreads();
    const int o = tid >> 2, tg = tid & 3;
    float oa[9] = {};
    for (int kc = 0; kc < 48; ++kc) {
        int k = kc >> 4, c = kc & 15;
        float th = theta[kc * 64 + o];
        const float* rp = &rs[k][c * TT + tg * 9];
#pragma unroll
        for (int j = 0; j < 9; ++j) oa[j] += th * rp[j];
    }
    float* ob = out + ((size_t)b * NN + n) * (COUT * TT);
#pragma unroll
    for (int j = 0; j < 9; ++j)
        ob[o * TT + tg * 9 + j] = fmaxf(oa[j], 0.f);
}

extern "C" void kernel_launch(void* const* d_in, const int* in_sizes, int n_in,
                              void* d_out, int out_size, void* d_ws, size_t ws_size,
                              hipStream_t stream) {
    const float* x     = (const float*)d_in[0];   // [B,N,CIN,T]
    const float* sat   = (const float*)d_in[1];   // [B,N,N]
    const float* cheb  = (const float*)d_in[2];   // [K,N,N]
    const float* theta = (const float*)d_in[3];   // [K,CIN,COUT]
    float* out = (float*)d_out;

    const size_t XT   = (size_t)NB * CT * NN;        //  9.4M ushorts (18.9 MB)
    const size_t ATF  = (size_t)KB * NN * NN;        // 50.3M (100.7 MB) full At
    const size_t ATNS = (size_t)KB * 512 * NN;       // 25.2M (50.3 MB) n-half chunk
    const size_t needA     = (XT + ATF) * 2;         // 119,537,664 B
    const size_t needSplit = (XT + ATNS) * 2;        //  69,206,016 B

    ushort* Xt = (ushort*)d_ws;
    ushort* At = Xt + XT;

    if (ws_size >= needA) {
        prep_x<<<dim3(144, NB), 256, 0, stream>>>(x, Xt);
        prep_a<<<dim3(256, KK), 256, 0, stream>>>(cheb, sat, At, 0, 1024);
        gemm1f<<<dim3(48, NB), 512, 0, stream>>>(At, Xt, theta, out, 0, 0, 1024);
    } else if (ws_size >= needSplit) {
        prep_x<<<dim3(144, NB), 256, 0, stream>>>(x, Xt);
        for (int half = 0; half < 2; ++half) {
            int nb = half * 512;
            prep_a<<<dim3(128, KK), 256, 0, stream>>>(cheb, sat, At, nb, 512);
            gemm1f<<<dim3(24, NB), 512, 0, stream>>>(At, Xt, theta, out, 1, nb, 512);
        }
    } else {
        naive_fused<<<dim3(NN, NB), 256, 0, stream>>>(x, sat, cheb, theta, out);
    }
}

// Round 5
// 384.582 us; speedup vs baseline: 1.2856x; 1.2856x over previous
//
#include <hip/hip_runtime.h>
#include <hip/hip_bf16.h>

// Problem constants
#define NB 16      // batch
#define NN 1024    // nodes
#define CIN 16
#define TT 36
#define KK 3
#define COUT 64
#define CT 576     // CIN*TT
#define KB 48      // KK*NB

typedef __attribute__((ext_vector_type(8))) short bf16x8;
typedef __attribute__((ext_vector_type(4))) float f32x4;

__device__ __forceinline__ unsigned short f2bf(float f) {
    union { float f; unsigned int u; } v; v.f = f;
    unsigned int r = v.u + 0x7FFF + ((v.u >> 16) & 1);
    return (unsigned short)(r >> 16);
}

// -------- prep_a: At[l][n - n_base][m] = bf16(cheb[k][m][n] * SAt[b][m][n]) --------
// One block per (k, 64x64 tile position); loops b=0..15 with the cheb tile pinned
// in registers; next-b sat load issued before the barrier (overlaps write-out).
__global__ __launch_bounds__(256) void prep_a(const float* __restrict__ cheb,
                                              const float* __restrict__ sat,
                                              ushort* __restrict__ At,
                                              int n_base, int rows) {
    __shared__ ushort tile[64][68];
    const int ntiles = rows >> 6;
    const int k = blockIdx.y;
    const int n0 = n_base + (blockIdx.x % ntiles) * 64;
    const int m0 = (blockIdx.x / ntiles) * 64;
    const int tid = threadIdx.x;

    size_t goff[4];
    float4 cv[4], sv[4];
#pragma unroll
    for (int i = 0; i < 4; ++i) {
        int f = i * 256 + tid;
        goff[i] = (size_t)(m0 + (f >> 4)) * NN + n0 + ((f & 15) << 2);
        cv[i] = *(const float4*)(cheb + (size_t)k * NN * NN + goff[i]);
        sv[i] = *(const float4*)(sat + goff[i]);      // b = 0
    }
    for (int b = 0; b < 16; ++b) {
#pragma unroll
        for (int i = 0; i < 4; ++i) {
            int f = i * 256 + tid;
            ushort4 u;
            u.x = f2bf(cv[i].x * sv[i].x); u.y = f2bf(cv[i].y * sv[i].y);
            u.z = f2bf(cv[i].z * sv[i].z); u.w = f2bf(cv[i].w * sv[i].w);
            *(ushort4*)&tile[f >> 4][(f & 15) << 2] = u;
        }
        if (b < 15) {
            const float* sa = sat + (size_t)(b + 1) * NN * NN;
#pragma unroll
            for (int i = 0; i < 4; ++i) sv[i] = *(const float4*)(sa + goff[i]);
        }
        __syncthreads();
        ushort* outp = At + (size_t)(k * 16 + b) * rows * NN;
#pragma unroll
        for (int i = 0; i < 4; ++i) {
            int f = i * 256 + tid;
            int n = f >> 4, m4 = (f & 15) << 2;
            ushort4 u;
            u.x = tile[m4 + 0][n]; u.y = tile[m4 + 1][n];
            u.z = tile[m4 + 2][n]; u.w = tile[m4 + 3][n];
            *(ushort4*)(outp + (size_t)(n0 - n_base + n) * NN + m0 + m4) = u;
        }
        __syncthreads();   // tile reused next b-iteration
    }
}

// -------- prep_x: Xt[b][ct'][m] = bf16(x[b][m][c][t]), ct' = t*16 + c --------
__global__ __launch_bounds__(256) void prep_x(const float* __restrict__ x,
                                              ushort* __restrict__ Xt) {
    __shared__ ushort tile[64][68];
    const int b = blockIdx.y;
    const int m0 = (blockIdx.x & 15) * 64;
    const int c0 = (blockIdx.x >> 4) * 64;
    const int tid = threadIdx.x;
    const float* xb = x + (size_t)b * NN * CT;
#pragma unroll
    for (int i = 0; i < 4; ++i) {
        int f = i * 256 + tid;
        int mr = f >> 4, c4 = (f & 15) << 2;
        float4 v = *(const float4*)(xb + (size_t)(m0 + mr) * CT + c0 + c4);
        ushort4 u;
        u.x = f2bf(v.x); u.y = f2bf(v.y); u.z = f2bf(v.z); u.w = f2bf(v.w);
        *(ushort4*)&tile[mr][c4] = u;
    }
    __syncthreads();
    ushort* outp = Xt + (size_t)b * CT * NN;
#pragma unroll
    for (int i = 0; i < 4; ++i) {
        int f = i * 256 + tid;
        int n = f >> 4, m4 = (f & 15) << 2;
        int ctlin = c0 + n;                     // = c*36 + t
        int c = ctlin / 36, t = ctlin - 36 * c;
        int ctp = t * 16 + c;                   // t-major permuted row
        ushort4 u;
        u.x = tile[m4 + 0][n]; u.y = tile[m4 + 1][n];
        u.z = tile[m4 + 2][n]; u.w = tile[m4 + 3][n];
        *(ushort4*)(outp + (size_t)ctp * NN + m0 + m4) = u;
    }
}

// -------- gemm1: rhs2[b][n][t][k*16+c] = sum_m At[n][m] * Xt[b][ct'][m] --------
// R5: ring-3 buffers with STAGE-FIRST + single barrier per K-step.
// R2 (2-buf, stage-after-compute, 2 barriers) and R3 (3-buf, stage-after, 2
// barriers) both kept the stage issue on the serial barrier tail (the m233-style
// 2-phase stall). Here STAGE(kt+2) is issued at the TOP of iter kt -- legal with
// ring-3 because slot (kt+2)%3 holds tile kt-1, whose readers all passed the
// end-of-iter-(kt-1) barrier. The stage issue then overlaps this iter's
// ds_read+MFMA, and each iter ends with ONE {vmcnt(5); s_barrier} (tile kt+1
// drained, kt+2's 5 loads stay in flight -- never 0 mid-loop).
// Tile BM=128(n) x BN=192(ct') x BK=64, 512 threads = 8 waves (2M x 4N).
// Swizzle (rule #21, both-sides): LDS dest linear; global SOURCE pre-swizzled
// chunk c -> c ^ (row&7); ds_read uses chunk' = q ^ (row&7).
// XCD swizzle: grid.x=24 (8 nt x 3 ctt), XCD = x%8; A-slice sharers at
// x, x+8, x+16 -> same XCD L2.
__global__ __launch_bounds__(512) void gemm1(const ushort* __restrict__ At,
                                             const ushort* __restrict__ Xt,
                                             ushort* __restrict__ rhs2,
                                             int nsplit, int n_base, int rows) {
    __shared__ ushort lds[3 * 320 * 64];          // 122,880 B (ring of 3 A+B buffers)
    const int tid = threadIdx.x;
    const int y = blockIdx.y;
    const int b = y / 3, k = y - 3 * b;           // Xt-sharing trios adjacent
    const int l = k * 16 + b;                     // At chunk index
    const int ntiles = rows >> 7;
    const int nt = blockIdx.x % ntiles;
    const int ctt = blockIdx.x / ntiles;
    const int nloc0 = nt * 128;
    const int ct0 = ctt * 192;
    const ushort* Ab = At + ((size_t)l * (nsplit ? rows : NN) + nloc0) * NN;
    const ushort* Bb = Xt + (size_t)b * CT * NN + (size_t)ct0 * NN;

    // staging geometry: slot s = (row = s>>3, chunk = s&7); 16B per slot.
    // source chunk pre-swizzled: c ^ (row&7)  (row&7 == srow&7 for +64k rows)
    const int srow = tid >> 3;                    // 0..63
    const int schunk = tid & 7;
    const int swz = schunk ^ (srow & 7);
    const ushort* a_src0 = Ab + (size_t)srow * NN + swz * 8;
    const ushort* b_src0 = Bb + (size_t)srow * NN + swz * 8;

    auto STAGE = [&](int kt, int p) {
        const int mk = kt * 64;
        ushort* base = lds + p * (320 * 64);
        const ushort* as = a_src0 + mk;
        const ushort* bs = b_src0 + mk;
#pragma unroll
        for (int i = 0; i < 2; ++i)               // A: 128 rows x 8 chunks
            __builtin_amdgcn_global_load_lds(
                (const __attribute__((address_space(1))) void*)(as + (size_t)i * 64 * NN),
                (__attribute__((address_space(3))) void*)(base + (tid + i * 512) * 8), 16, 0, 0);
#pragma unroll
        for (int i = 0; i < 3; ++i)               // B: 192 rows x 8 chunks
            __builtin_amdgcn_global_load_lds(
                (const __attribute__((address_space(1))) void*)(bs + (size_t)i * 64 * NN),
                (__attribute__((address_space(3))) void*)(base + 128 * 64 + (tid + i * 512) * 8), 16, 0, 0);
    };

    const int w = tid >> 6, lane = tid & 63;
    const int wr = w >> 2, wc = w & 3;            // 2 x 4 wave grid
    const int lrow = lane & 15, quad = lane >> 4;
    const int koff0 = ((quad ^ (lrow & 7)) << 3); // swizzled k-chunk, kk0=0
    f32x4 acc[4][3] = {};

    STAGE(0, 0);                                  //  5 in flight
    STAGE(1, 1);                                  // 10 in flight
    asm volatile("s_waitcnt vmcnt(5)\n\ts_barrier" ::: "memory");   // tile 0 ready

    for (int kt = 0; kt < 16; ++kt) {
        if (kt + 2 < 16)
            STAGE(kt + 2, (kt + 2) % 3);          // issue EARLY: overlaps compute below
        const ushort* bufA = lds + (kt % 3) * (320 * 64);
        const ushort* bufB = bufA + 128 * 64;
#pragma unroll
        for (int kp = 0; kp < 2; ++kp) {
            const int koff = koff0 ^ (kp << 5);   // chunk ^= 4 for kk0=32
            bf16x8 af[4], bfr[3];
#pragma unroll
            for (int mi = 0; mi < 4; ++mi)
                af[mi] = *(const bf16x8*)&bufA[(wr * 64 + mi * 16 + lrow) * 64 + koff];
#pragma unroll
            for (int ni = 0; ni < 3; ++ni)
                bfr[ni] = *(const bf16x8*)&bufB[(wc * 48 + ni * 16 + lrow) * 64 + koff];
            __builtin_amdgcn_s_setprio(1);
#pragma unroll
            for (int mi = 0; mi < 4; ++mi)
#pragma unroll
                for (int ni = 0; ni < 3; ++ni)
                    acc[mi][ni] = __builtin_amdgcn_mfma_f32_16x16x32_bf16(
                        af[mi], bfr[ni], acc[mi][ni], 0, 0, 0);
            __builtin_amdgcn_s_setprio(0);
        }
        // ONE sync point per iter: drain tile kt+1 (keep kt+2's 5 in flight),
        // barrier doubles as "all waves done reading slot kt%3".
        if (kt + 2 < 16)
            asm volatile("s_waitcnt vmcnt(5)\n\ts_barrier" ::: "memory");
        else if (kt + 1 < 16)
            asm volatile("s_waitcnt vmcnt(0)\n\ts_barrier" ::: "memory");
        else
            asm volatile("s_barrier" ::: "memory");
    }

    // stage C (bf16) into LDS (reuse pipeline buffers; row stride 200 breaks banks)
    ushort* cs = lds;
#pragma unroll
    for (int mi = 0; mi < 4; ++mi)
#pragma unroll
        for (int ni = 0; ni < 3; ++ni)
#pragma unroll
            for (int r = 0; r < 4; ++r)
                cs[(wr * 64 + mi * 16 + quad * 4 + r) * 200 + wc * 48 + ni * 16 + lrow] =
                    f2bf(acc[mi][ni][r]);
    __syncthreads();

    // cooperative store: 128 n x 12 t x 32B (16 c) segments into rhs2[b][n][t][48]
    for (int f = tid; f < 1536; f += 512) {
        int n = f / 12, tl = f - 12 * (f / 12);
        int t = ctt * 12 + tl;
        uint4 v0 = *(const uint4*)&cs[n * 200 + tl * 16];
        uint4 v1 = *(const uint4*)&cs[n * 200 + tl * 16 + 8];
        size_t g = (((size_t)b * NN + n_base + nloc0 + n) * 36 + t) * 48 + k * 16;
        *(uint4*)(rhs2 + g) = v0;
        *(uint4*)(rhs2 + g + 8) = v1;
    }
}

// -------- apply_mfma2: out[b,n,o,t] = relu(sum_kc rhs2[b,n,t,kc] * theta[kc,o]) --------
// 16 bn per block (4 per wave, sequential). Stores LDS-staged for 1KB bursts.
__global__ __launch_bounds__(256) void apply_mfma2(const ushort* __restrict__ rhs2,
                                                   const float* __restrict__ theta,
                                                   float* __restrict__ out) {
    __shared__ ushort thT[64 * 72];       // [o][kc], kc in [48,64) zeroed
    __shared__ float ostage[4][64 * 36];  // per-wave staging, 9216 B each
    const int tid = threadIdx.x;
    for (int f = tid; f < 64 * 64; f += 256) {
        int o = f >> 6, kc = f & 63;
        thT[o * 72 + kc] = f2bf((kc < 48) ? theta[kc * 64 + o] : 0.f);
    }
    __syncthreads();
    const int w = tid >> 6, lane = tid & 63;
    const int lrow = lane & 15, quad = lane >> 4;

    bf16x8 a[4][2];
#pragma unroll
    for (int mi = 0; mi < 4; ++mi)
#pragma unroll
        for (int kc = 0; kc < 2; ++kc)
            a[mi][kc] = *(const bf16x8*)&thT[(mi * 16 + lrow) * 72 + kc * 32 + quad * 8];

    float* ost = &ostage[w][0];
    for (int j = 0; j < 4; ++j) {
        const int bn = blockIdx.x * 16 + w * 4 + j;
        const ushort* rrow = rhs2 + (size_t)bn * (36 * 48);
        f32x4 acc[4][3] = {};
#pragma unroll
        for (int ni = 0; ni < 3; ++ni)
#pragma unroll
            for (int kc = 0; kc < 2; ++kc) {
                // t-col >= 36 and kc-pad read in-bounds garbage (rhs2 is first in
                // ws, Xt follows): masked by zero theta rows / t<36 staging guard.
                bf16x8 bf = *(const bf16x8*)(rrow + (ni * 16 + lrow) * 48 + kc * 32 + quad * 8);
#pragma unroll
                for (int mi = 0; mi < 4; ++mi)
                    acc[mi][ni] = __builtin_amdgcn_mfma_f32_16x16x32_bf16(
                        a[mi][kc], bf, acc[mi][ni], 0, 0, 0);
            }
#pragma unroll
        for (int mi = 0; mi < 4; ++mi)
#pragma unroll
            for (int ni = 0; ni < 3; ++ni)
#pragma unroll
                for (int r = 0; r < 4; ++r) {
                    int t = ni * 16 + lrow;
                    if (t < 36)
                        ost[(mi * 16 + quad * 4 + r) * 36 + t] = fmaxf(acc[mi][ni][r], 0.f);
                }
        // wave-local LDS write->read across lanes: drain lgkm explicitly
        asm volatile("s_waitcnt lgkmcnt(0)" ::: "memory");
        float* ob = out + (size_t)bn * (COUT * TT);
#pragma unroll
        for (int q = 0; q < 9; ++q) {
            int f = q * 64 + lane;            // 576 float4 per row
            *(float4*)&ob[f * 4] = *(const float4*)&ost[f * 4];
        }
    }
}

// -------- naive fallback: zero workspace, fully fused --------
__global__ __launch_bounds__(256) void naive_fused(const float* __restrict__ x,
                                                   const float* __restrict__ sat,
                                                   const float* __restrict__ cheb,
                                                   const float* __restrict__ theta,
                                                   float* __restrict__ out) {
    __shared__ float wgt[3][1024];
    __shared__ float rs[3][576];
    const int tid = threadIdx.x;
    const int n = blockIdx.x, b = blockIdx.y;
    for (int f = tid; f < 3 * 1024; f += 256) {
        int k = f >> 10, m = f & 1023;
        wgt[k][m] = cheb[(size_t)k * NN * NN + (size_t)m * NN + n] *
                    sat[(size_t)b * NN * NN + (size_t)m * NN + n];
    }
    __syncthreads();
    float a0[3] = {}, a1[3] = {}, a2[3] = {};
    const float* xb = x + (size_t)b * NN * CT;
    for (int m = 0; m < 1024; ++m) {
        const float* xr = xb + (size_t)m * CT;
        float x0 = xr[tid];
        float x1 = xr[256 + tid];
        float x2 = (tid < 64) ? xr[512 + tid] : 0.f;
#pragma unroll
        for (int k = 0; k < 3; ++k) {
            float wm = wgt[k][m];
            a0[k] += wm * x0; a1[k] += wm * x1; a2[k] += wm * x2;
        }
    }
#pragma unroll
    for (int k = 0; k < 3; ++k) {
        rs[k][tid] = a0[k];
        rs[k][256 + tid] = a1[k];
        if (tid < 64) rs[k][512 + tid] = a2[k];
    }
    __syncthreads();
    const int o = tid >> 2, tg = tid & 3;
    float oa[9] = {};
    for (int kc = 0; kc < 48; ++kc) {
        int k = kc >> 4, c = kc & 15;
        float th = theta[kc * 64 + o];
        const float* rp = &rs[k][c * TT + tg * 9];
#pragma unroll
        for (int j = 0; j < 9; ++j) oa[j] += th * rp[j];
    }
    float* ob = out + ((size_t)b * NN + n) * (COUT * TT);
#pragma unroll
    for (int j = 0; j < 9; ++j)
        ob[o * TT + tg * 9 + j] = fmaxf(oa[j], 0.f);
}

extern "C" void kernel_launch(void* const* d_in, const int* in_sizes, int n_in,
                              void* d_out, int out_size, void* d_ws, size_t ws_size,
                              hipStream_t stream) {
    const float* x     = (const float*)d_in[0];   // [B,N,CIN,T]
    const float* sat   = (const float*)d_in[1];   // [B,N,N]
    const float* cheb  = (const float*)d_in[2];   // [K,N,N]
    const float* theta = (const float*)d_in[3];   // [K,CIN,COUT]
    float* out = (float*)d_out;

    const size_t RHS2 = (size_t)NB * NN * 36 * 48;   // 28.3M ushorts (56.6 MB)
    const size_t XT   = (size_t)NB * CT * NN;        //  9.4M (18.9 MB)
    const size_t ATF  = (size_t)KB * NN * NN;        // 50.3M (100.7 MB) full At
    const size_t ATNS = (size_t)KB * 512 * NN;       // 25.2M (50.3 MB) n-half chunk
    const size_t needA     = (RHS2 + XT + ATF) * 2;  // 176,160,768 B
    const size_t needSplit = (RHS2 + XT + ATNS) * 2; // 125,829,120 B

    // layout: rhs2 FIRST (apply's bounded over-reads land in Xt), then Xt, At
    ushort* rhs2 = (ushort*)d_ws;
    ushort* Xt   = rhs2 + RHS2;
    ushort* At   = Xt + XT;

    if (ws_size >= needA) {
        prep_x<<<dim3(144, NB), 256, 0, stream>>>(x, Xt);
        prep_a<<<dim3(256, KK), 256, 0, stream>>>(cheb, sat, At, 0, 1024);
        gemm1<<<dim3(24, KB), 512, 0, stream>>>(At, Xt, rhs2, 0, 0, 1024);
        apply_mfma2<<<dim3(NB * NN / 16), 256, 0, stream>>>(rhs2, theta, out);
    } else if (ws_size >= needSplit) {
        prep_x<<<dim3(144, NB), 256, 0, stream>>>(x, Xt);
        for (int half = 0; half < 2; ++half) {
            int nb = half * 512;
            prep_a<<<dim3(128, KK), 256, 0, stream>>>(cheb, sat, At, nb, 512);
            gemm1<<<dim3(12, KB), 512, 0, stream>>>(At, Xt, rhs2, 1, nb, 512);
        }
        apply_mfma2<<<dim3(NB * NN / 16), 256, 0, stream>>>(rhs2, theta, out);
    } else {
        naive_fused<<<dim3(NN, NB), 256, 0, stream>>>(x, sat, cheb, theta, out);
    }
}

// Round 6
// 376.563 us; speedup vs baseline: 1.3130x; 1.0213x over previous
//
#include <hip/hip_runtime.h>
#include <hip/hip_bf16.h>

// Problem constants
#define NB 16      // batch
#define NN 1024    // nodes
#define CIN 16
#define TT 36
#define KK 3
#define COUT 64
#define CT 576     // CIN*TT
#define KB 48      // KK*NB

typedef __attribute__((ext_vector_type(8))) short bf16x8;
typedef __attribute__((ext_vector_type(4))) float f32x4;

__device__ __forceinline__ unsigned short f2bf(float f) {
    union { float f; unsigned int u; } v; v.f = f;
    unsigned int r = v.u + 0x7FFF + ((v.u >> 16) & 1);
    return (unsigned short)(r >> 16);
}

// -------- prep_a: At[l][n - n_base][m] = bf16(cheb[k][m][n] * SAt[b][m][n]) --------
// One block per (k, 64x64 tile position); loops b=0..15 with the cheb tile pinned
// in registers; next-b sat load issued before the barrier (overlaps write-out).
__global__ __launch_bounds__(256) void prep_a(const float* __restrict__ cheb,
                                              const float* __restrict__ sat,
                                              ushort* __restrict__ At,
                                              int n_base, int rows) {
    __shared__ ushort tile[64][68];
    const int ntiles = rows >> 6;
    const int k = blockIdx.y;
    const int n0 = n_base + (blockIdx.x % ntiles) * 64;
    const int m0 = (blockIdx.x / ntiles) * 64;
    const int tid = threadIdx.x;

    size_t goff[4];
    float4 cv[4], sv[4];
#pragma unroll
    for (int i = 0; i < 4; ++i) {
        int f = i * 256 + tid;
        goff[i] = (size_t)(m0 + (f >> 4)) * NN + n0 + ((f & 15) << 2);
        cv[i] = *(const float4*)(cheb + (size_t)k * NN * NN + goff[i]);
        sv[i] = *(const float4*)(sat + goff[i]);      // b = 0
    }
    for (int b = 0; b < 16; ++b) {
#pragma unroll
        for (int i = 0; i < 4; ++i) {
            int f = i * 256 + tid;
            ushort4 u;
            u.x = f2bf(cv[i].x * sv[i].x); u.y = f2bf(cv[i].y * sv[i].y);
            u.z = f2bf(cv[i].z * sv[i].z); u.w = f2bf(cv[i].w * sv[i].w);
            *(ushort4*)&tile[f >> 4][(f & 15) << 2] = u;
        }
        if (b < 15) {
            const float* sa = sat + (size_t)(b + 1) * NN * NN;
#pragma unroll
            for (int i = 0; i < 4; ++i) sv[i] = *(const float4*)(sa + goff[i]);
        }
        __syncthreads();
        ushort* outp = At + (size_t)(k * 16 + b) * rows * NN;
#pragma unroll
        for (int i = 0; i < 4; ++i) {
            int f = i * 256 + tid;
            int n = f >> 4, m4 = (f & 15) << 2;
            ushort4 u;
            u.x = tile[m4 + 0][n]; u.y = tile[m4 + 1][n];
            u.z = tile[m4 + 2][n]; u.w = tile[m4 + 3][n];
            *(ushort4*)(outp + (size_t)(n0 - n_base + n) * NN + m0 + m4) = u;
        }
        __syncthreads();   // tile reused next b-iteration
    }
}

// -------- prep_x: Xt[b][ct'][m] = bf16(x[b][m][c][t]), ct' = t*16 + c --------
__global__ __launch_bounds__(256) void prep_x(const float* __restrict__ x,
                                              ushort* __restrict__ Xt) {
    __shared__ ushort tile[64][68];
    const int b = blockIdx.y;
    const int m0 = (blockIdx.x & 15) * 64;
    const int c0 = (blockIdx.x >> 4) * 64;
    const int tid = threadIdx.x;
    const float* xb = x + (size_t)b * NN * CT;
#pragma unroll
    for (int i = 0; i < 4; ++i) {
        int f = i * 256 + tid;
        int mr = f >> 4, c4 = (f & 15) << 2;
        float4 v = *(const float4*)(xb + (size_t)(m0 + mr) * CT + c0 + c4);
        ushort4 u;
        u.x = f2bf(v.x); u.y = f2bf(v.y); u.z = f2bf(v.z); u.w = f2bf(v.w);
        *(ushort4*)&tile[mr][c4] = u;
    }
    __syncthreads();
    ushort* outp = Xt + (size_t)b * CT * NN;
#pragma unroll
    for (int i = 0; i < 4; ++i) {
        int f = i * 256 + tid;
        int n = f >> 4, m4 = (f & 15) << 2;
        int ctlin = c0 + n;                     // = c*36 + t
        int c = ctlin / 36, t = ctlin - 36 * c;
        int ctp = t * 16 + c;                   // t-major permuted row
        ushort4 u;
        u.x = tile[m4 + 0][n]; u.y = tile[m4 + 1][n];
        u.z = tile[m4 + 2][n]; u.w = tile[m4 + 3][n];
        *(ushort4*)(outp + (size_t)ctp * NN + m0 + m4) = u;
    }
}

// -------- gemm1: rhs2[b][n][t][k*16+c] = sum_m At_k[n][m] * Xt[b][ct'][m] --------
// R6: k-FUSED tile (R4's numerically-verified main loop: BM=64 n, all 3 k in one
// block, acc[3][2][3], B-frags shared across k) + R5's verified stage-early
// ring-3 schedule + a NEW rhs2 epilogue (per-wave LDS restage -> full 96B kc-row
// stores). vs R2/R5 per-k tiling: staged bytes 737->590 MB, MFMA per staged KB
// 4.8->6.0, blocks 1152->768 = exactly 3 rounds at 1 block/CU. R4's slow theta
// epilogue (460MB write scatter) is NOT used -- apply_mfma2 stays.
// LDS: ring-3 x [A0|A1|A2 (64x64) | B (192x64)] bf16 = 3 x 48KB = 144 KB.
// Schedule: top-of-iter STAGE(kt+2) into slot (kt+2)%3 (holds tile kt-1, whose
// readers passed the end-of-iter-(kt-1) barrier -> legal); end-of-iter ONE
// {vmcnt(6); s_barrier} (tile kt+1 drained, kt+2's 6 loads in flight; never 0).
// Swizzle (rule #21 both-sides): LDS dest linear, source chunk c^(row&7),
// ds_read chunk (kp*4+quad)^(lrow&7).
// XCD: grid.x=48 (16 nt x 3 ctt), 48%8==0 -> XCD = x%8; A-sharers (same nt,
// 3 ctt) at x, x+16, x+32 -> same XCD L2.
__global__ __launch_bounds__(512) void gemm1(const ushort* __restrict__ At,
                                             const ushort* __restrict__ Xt,
                                             ushort* __restrict__ rhs2,
                                             int nsplit, int n_base, int rows) {
    __shared__ ushort lds[3 * 384 * 64];          // 147,456 B
    const int tid = threadIdx.x;
    const int b = blockIdx.y;
    const int ntiles = rows >> 6;
    const int nt = blockIdx.x % ntiles;
    const int ctt = blockIdx.x / ntiles;
    const int nloc0 = nt * 64;
    const int ct0 = ctt * 192;
    const int atrows = nsplit ? rows : NN;

    // staging: thread -> (row = tid>>3, chunk = tid&7), 16B slots; source chunk
    // pre-swizzled c ^ (row&7); LDS dest LINEAR.
    const int srow = tid >> 3, schunk = tid & 7;
    const int swz = schunk ^ (srow & 7);
    const ushort* a_src[3];
#pragma unroll
    for (int k = 0; k < 3; ++k)
        a_src[k] = At + ((size_t)(k * 16 + b) * atrows + nloc0 + srow) * NN + swz * 8;
    const ushort* b_src = Xt + (size_t)b * CT * NN + (size_t)(ct0 + srow) * NN + swz * 8;

    auto STAGE = [&](int kt, int p) {
        const int mk = kt * 64;
        ushort* base = lds + p * (384 * 64);
#pragma unroll
        for (int k = 0; k < 3; ++k)        // A_k: 64 rows x 8 chunks = 512 slots
            __builtin_amdgcn_global_load_lds(
                (const __attribute__((address_space(1))) void*)(a_src[k] + mk),
                (__attribute__((address_space(3))) void*)(base + k * 4096 + tid * 8), 16, 0, 0);
#pragma unroll
        for (int i = 0; i < 3; ++i)        // B: 192 rows x 8 chunks = 1536 slots
            __builtin_amdgcn_global_load_lds(
                (const __attribute__((address_space(1))) void*)(b_src + (size_t)i * 64 * NN + mk),
                (__attribute__((address_space(3))) void*)(base + 3 * 4096 + (tid + i * 512) * 8), 16, 0, 0);
    };

    const int w = tid >> 6, lane = tid & 63;
    const int wr = w >> 2, wc = w & 3;            // 2 x 4 wave grid: 32n x 48ct
    const int lrow = lane & 15, quad = lane >> 4;
    const int s3 = lrow & 7;
    f32x4 acc[3][2][3] = {};                      // [k][mi(n)][ni(ct)]

    STAGE(0, 0);                                  //  6 in flight
    STAGE(1, 1);                                  // 12 in flight
    asm volatile("s_waitcnt vmcnt(6)\n\ts_barrier" ::: "memory");   // tile 0 ready

    for (int kt = 0; kt < 16; ++kt) {
        if (kt + 2 < 16)
            STAGE(kt + 2, (kt + 2) % 3);          // issue EARLY: overlaps compute
        const ushort* bufA = lds + (kt % 3) * (384 * 64);
        const ushort* bufB = bufA + 3 * 4096;
#pragma unroll
        for (int kp = 0; kp < 2; ++kp) {
            const int koff = (((kp * 4 + quad) ^ s3) << 3);   // swizzled k-chunk
            bf16x8 af[3][2], bfr[3];
#pragma unroll
            for (int k = 0; k < 3; ++k)
#pragma unroll
                for (int mi = 0; mi < 2; ++mi)
                    af[k][mi] = *(const bf16x8*)&bufA[k * 4096 + (wr * 32 + mi * 16 + lrow) * 64 + koff];
#pragma unroll
            for (int ni = 0; ni < 3; ++ni)
                bfr[ni] = *(const bf16x8*)&bufB[(wc * 48 + ni * 16 + lrow) * 64 + koff];
            __builtin_amdgcn_s_setprio(1);
#pragma unroll
            for (int k = 0; k < 3; ++k)
#pragma unroll
                for (int mi = 0; mi < 2; ++mi)
#pragma unroll
                    for (int ni = 0; ni < 3; ++ni)
                        acc[k][mi][ni] = __builtin_amdgcn_mfma_f32_16x16x32_bf16(
                            af[k][mi], bfr[ni], acc[k][mi][ni], 0, 0, 0);
            __builtin_amdgcn_s_setprio(0);
        }
        // ONE sync point per iter: drain tile kt+1, keep kt+2's 6 in flight;
        // barrier doubles as "all waves done reading slot kt%3".
        if (kt + 2 < 16)
            asm volatile("s_waitcnt vmcnt(6)\n\ts_barrier" ::: "memory");
        else if (kt + 1 < 16)
            asm volatile("s_waitcnt vmcnt(0)\n\ts_barrier" ::: "memory");
        else
            asm volatile("s_barrier" ::: "memory");
    }

    // ---- epilogue: per-wave restage [n(32)][t(3)][kc(48)] (9216 B/wave), then
    // cooperative 16B stores of full 96B kc-rows (3 consecutive t = 288B bursts).
    ushort* sc = lds + w * 4608;
#pragma unroll
    for (int k = 0; k < 3; ++k)
#pragma unroll
        for (int mi = 0; mi < 2; ++mi)
#pragma unroll
            for (int ni = 0; ni < 3; ++ni)
#pragma unroll
                for (int r = 0; r < 4; ++r)
                    sc[((mi * 16 + quad * 4 + r) * 3 + ni) * 48 + k * 16 + lrow] =
                        f2bf(acc[k][mi][ni][r]);
    // wave-local LDS write->read: drain lgkm (no cross-wave sharing -> no barrier)
    asm volatile("s_waitcnt lgkmcnt(0)" ::: "memory");
    const int n_g0 = n_base + nloc0 + wr * 32;
    const int t_g0 = ctt * 12 + wc * 3;
#pragma unroll
    for (int i = 0; i < 9; ++i) {
        int seg = i * 64 + lane;          // 576 x 16B segments per wave
        int off = seg * 8;                // ushort offset in sc
        int nl = off / 144;               // 144 = 3t * 48kc
        int rem = off - nl * 144;
        int tl = rem / 48, kcol = rem - tl * 48;
        size_t g = (((size_t)b * NN + n_g0 + nl) * 36 + (t_g0 + tl)) * 48 + kcol;
        *(uint4*)(rhs2 + g) = *(const uint4*)&sc[off];
    }
}

// -------- apply_mfma2: out[b,n,o,t] = relu(sum_kc rhs2[b,n,t,kc] * theta[kc,o]) --------
// 16 bn per block (4 per wave, sequential). Stores LDS-staged for 1KB bursts.
__global__ __launch_bounds__(256) void apply_mfma2(const ushort* __restrict__ rhs2,
                                                   const float* __restrict__ theta,
                                                   float* __restrict__ out) {
    __shared__ ushort thT[64 * 72];       // [o][kc], kc in [48,64) zeroed
    __shared__ float ostage[4][64 * 36];  // per-wave staging, 9216 B each
    const int tid = threadIdx.x;
    for (int f = tid; f < 64 * 64; f += 256) {
        int o = f >> 6, kc = f & 63;
        thT[o * 72 + kc] = f2bf((kc < 48) ? theta[kc * 64 + o] : 0.f);
    }
    __syncthreads();
    const int w = tid >> 6, lane = tid & 63;
    const int lrow = lane & 15, quad = lane >> 4;

    bf16x8 a[4][2];
#pragma unroll
    for (int mi = 0; mi < 4; ++mi)
#pragma unroll
        for (int kc = 0; kc < 2; ++kc)
            a[mi][kc] = *(const bf16x8*)&thT[(mi * 16 + lrow) * 72 + kc * 32 + quad * 8];

    float* ost = &ostage[w][0];
    for (int j = 0; j < 4; ++j) {
        const int bn = blockIdx.x * 16 + w * 4 + j;
        const ushort* rrow = rhs2 + (size_t)bn * (36 * 48);
        f32x4 acc[4][3] = {};
#pragma unroll
        for (int ni = 0; ni < 3; ++ni)
#pragma unroll
            for (int kc = 0; kc < 2; ++kc) {
                // t-col >= 36 and kc-pad read in-bounds garbage (rhs2 is first in
                // ws, Xt follows): masked by zero theta rows / t<36 staging guard.
                bf16x8 bf = *(const bf16x8*)(rrow + (ni * 16 + lrow) * 48 + kc * 32 + quad * 8);
#pragma unroll
                for (int mi = 0; mi < 4; ++mi)
                    acc[mi][ni] = __builtin_amdgcn_mfma_f32_16x16x32_bf16(
                        a[mi][kc], bf, acc[mi][ni], 0, 0, 0);
            }
#pragma unroll
        for (int mi = 0; mi < 4; ++mi)
#pragma unroll
            for (int ni = 0; ni < 3; ++ni)
#pragma unroll
                for (int r = 0; r < 4; ++r) {
                    int t = ni * 16 + lrow;
                    if (t < 36)
                        ost[(mi * 16 + quad * 4 + r) * 36 + t] = fmaxf(acc[mi][ni][r], 0.f);
                }
        // wave-local LDS write->read across lanes: drain lgkm explicitly
        asm volatile("s_waitcnt lgkmcnt(0)" ::: "memory");
        float* ob = out + (size_t)bn * (COUT * TT);
#pragma unroll
        for (int q = 0; q < 9; ++q) {
            int f = q * 64 + lane;            // 576 float4 per row
            *(float4*)&ob[f * 4] = *(const float4*)&ost[f * 4];
        }
    }
}

// -------- naive fallback: zero workspace, fully fused --------
__global__ __launch_bounds__(256) void naive_fused(const float* __restrict__ x,
                                                   const float* __restrict__ sat,
                                                   const float* __restrict__ cheb,
                                                   const float* __restrict__ theta,
                                                   float* __restrict__ out) {
    __shared__ float wgt[3][1024];
    __shared__ float rs[3][576];
    const int tid = threadIdx.x;
    const int n = blockIdx.x, b = blockIdx.y;
    for (int f = tid; f < 3 * 1024; f += 256) {
        int k = f >> 10, m = f & 1023;
        wgt[k][m] = cheb[(size_t)k * NN * NN + (size_t)m * NN + n] *
                    sat[(size_t)b * NN * NN + (size_t)m * NN + n];
    }
    __syncthreads();
    float a0[3] = {}, a1[3] = {}, a2[3] = {};
    const float* xb = x + (size_t)b * NN * CT;
    for (int m = 0; m < 1024; ++m) {
        const float* xr = xb + (size_t)m * CT;
        float x0 = xr[tid];
        float x1 = xr[256 + tid];
        float x2 = (tid < 64) ? xr[512 + tid] : 0.f;
#pragma unroll
        for (int k = 0; k < 3; ++k) {
            float wm = wgt[k][m];
            a0[k] += wm * x0; a1[k] += wm * x1; a2[k] += wm * x2;
        }
    }
#pragma unroll
    for (int k = 0; k < 3; ++k) {
        rs[k][tid] = a0[k];
        rs[k][256 + tid] = a1[k];
        if (tid < 64) rs[k][512 + tid] = a2[k];
    }
    __syncthreads();
    const int o = tid >> 2, tg = tid & 3;
    float oa[9] = {};
    for (int kc = 0; kc < 48; ++kc) {
        int k = kc >> 4, c = kc & 15;
        float th = theta[kc * 64 + o];
        const float* rp = &rs[k][c * TT + tg * 9];
#pragma unroll
        for (int j = 0; j < 9; ++j) oa[j] += th * rp[j];
    }
    float* ob = out + ((size_t)b * NN + n) * (COUT * TT);
#pragma unroll
    for (int j = 0; j < 9; ++j)
        ob[o * TT + tg * 9 + j] = fmaxf(oa[j], 0.f);
}

extern "C" void kernel_launch(void* const* d_in, const int* in_sizes, int n_in,
                              void* d_out, int out_size, void* d_ws, size_t ws_size,
                              hipStream_t stream) {
    const float* x     = (const float*)d_in[0];   // [B,N,CIN,T]
    const float* sat   = (const float*)d_in[1];   // [B,N,N]
    const float* cheb  = (const float*)d_in[2];   // [K,N,N]
    const float* theta = (const float*)d_in[3];   // [K,CIN,COUT]
    float* out = (float*)d_out;

    const size_t RHS2 = (size_t)NB * NN * 36 * 48;   // 28.3M ushorts (56.6 MB)
    const size_t XT   = (size_t)NB * CT * NN;        //  9.4M (18.9 MB)
    const size_t ATF  = (size_t)KB * NN * NN;        // 50.3M (100.7 MB) full At
    const size_t ATNS = (size_t)KB * 512 * NN;       // 25.2M (50.3 MB) n-half chunk
    const size_t needA     = (RHS2 + XT + ATF) * 2;  // 176,160,768 B
    const size_t needSplit = (RHS2 + XT + ATNS) * 2; // 125,829,120 B

    // layout: rhs2 FIRST (apply's bounded over-reads land in Xt), then Xt, At
    ushort* rhs2 = (ushort*)d_ws;
    ushort* Xt   = rhs2 + RHS2;
    ushort* At   = Xt + XT;

    if (ws_size >= needA) {
        prep_x<<<dim3(144, NB), 256, 0, stream>>>(x, Xt);
        prep_a<<<dim3(256, KK), 256, 0, stream>>>(cheb, sat, At, 0, 1024);
        gemm1<<<dim3(48, NB), 512, 0, stream>>>(At, Xt, rhs2, 0, 0, 1024);
        apply_mfma2<<<dim3(NB * NN / 16), 256, 0, stream>>>(rhs2, theta, out);
    } else if (ws_size >= needSplit) {
        prep_x<<<dim3(144, NB), 256, 0, stream>>>(x, Xt);
        for (int half = 0; half < 2; ++half) {
            int nb = half * 512;
            prep_a<<<dim3(128, KK), 256, 0, stream>>>(cheb, sat, At, nb, 512);
            gemm1<<<dim3(24, NB), 512, 0, stream>>>(At, Xt, rhs2, 1, nb, 512);
        }
        apply_mfma2<<<dim3(NB * NN / 16), 256, 0, stream>>>(rhs2, theta, out);
    } else {
        naive_fused<<<dim3(NN, NB), 256, 0, stream>>>(x, sat, cheb, theta, out);
    }
}

// Round 7
// 373.578 us; speedup vs baseline: 1.3235x; 1.0080x over previous
//
#include <hip/hip_runtime.h>
#include <hip/hip_bf16.h>

// Problem constants
#define NB 16      // batch
#define NN 1024    // nodes
#define CIN 16
#define TT 36
#define KK 3
#define COUT 64
#define CT 576     // CIN*TT
#define KB 48      // KK*NB

typedef __attribute__((ext_vector_type(8))) short bf16x8;
typedef __attribute__((ext_vector_type(4))) float f32x4;

__device__ __forceinline__ unsigned short f2bf(float f) {
    union { float f; unsigned int u; } v; v.f = f;
    unsigned int r = v.u + 0x7FFF + ((v.u >> 16) & 1);
    return (unsigned short)(r >> 16);
}

// -------- prep_both: fused prep_a + prep_x (independent -> one dispatch) --------
// R7: prep_x (11us) and prep_a (~40us) have no data dependence; merging overlaps
// prep_x under prep_a's tail capacity and removes one launch gap.
// Blocks [0, na): prep_a body. flat id = k*(ntiles*16) + bx with ntiles*16 in
// {256,128} == 0 mod 8 -> the 3 k-blocks of one tile position keep the same XCD
// residue (sat-tile L2 sharing preserved from R1).
// Blocks [na, na+2304): prep_x body (only when do_x != 0).
__global__ __launch_bounds__(256) void prep_both(const float* __restrict__ cheb,
                                                 const float* __restrict__ sat,
                                                 ushort* __restrict__ At,
                                                 const float* __restrict__ x,
                                                 ushort* __restrict__ Xt,
                                                 int n_base, int rows, int na_blocks) {
    __shared__ ushort tile[64][68];
    const int tid = threadIdx.x;
    const int bid = blockIdx.x;

    if (bid < na_blocks) {
        // ---------------- prep_a: At[l][n-n_base][m] = bf16(cheb*sat) ----------------
        const int ntiles = rows >> 6;
        const int per_k = ntiles * 16;
        const int k = bid / per_k;
        const int bx = bid - k * per_k;
        const int n0 = n_base + (bx % ntiles) * 64;
        const int m0 = (bx / ntiles) * 64;

        size_t goff[4];
        float4 cv[4], sv[4];
#pragma unroll
        for (int i = 0; i < 4; ++i) {
            int f = i * 256 + tid;
            goff[i] = (size_t)(m0 + (f >> 4)) * NN + n0 + ((f & 15) << 2);
            cv[i] = *(const float4*)(cheb + (size_t)k * NN * NN + goff[i]);
            sv[i] = *(const float4*)(sat + goff[i]);      // b = 0
        }
        for (int b = 0; b < 16; ++b) {
#pragma unroll
            for (int i = 0; i < 4; ++i) {
                int f = i * 256 + tid;
                ushort4 u;
                u.x = f2bf(cv[i].x * sv[i].x); u.y = f2bf(cv[i].y * sv[i].y);
                u.z = f2bf(cv[i].z * sv[i].z); u.w = f2bf(cv[i].w * sv[i].w);
                *(ushort4*)&tile[f >> 4][(f & 15) << 2] = u;
            }
            if (b < 15) {
                const float* sa = sat + (size_t)(b + 1) * NN * NN;
#pragma unroll
                for (int i = 0; i < 4; ++i) sv[i] = *(const float4*)(sa + goff[i]);
            }
            __syncthreads();
            ushort* outp = At + (size_t)(k * 16 + b) * rows * NN;
#pragma unroll
            for (int i = 0; i < 4; ++i) {
                int f = i * 256 + tid;
                int n = f >> 4, m4 = (f & 15) << 2;
                ushort4 u;
                u.x = tile[m4 + 0][n]; u.y = tile[m4 + 1][n];
                u.z = tile[m4 + 2][n]; u.w = tile[m4 + 3][n];
                *(ushort4*)(outp + (size_t)(n0 - n_base + n) * NN + m0 + m4) = u;
            }
            __syncthreads();   // tile reused next b-iteration
        }
    } else {
        // ---------------- prep_x: Xt[b][t*16+c][m] = bf16(x[b][m][c][t]) ------------
        const int f0 = bid - na_blocks;
        const int b = f0 / 144;
        const int bx = f0 - b * 144;
        const int m0 = (bx & 15) * 64;
        const int c0 = (bx >> 4) * 64;
        const float* xb = x + (size_t)b * NN * CT;
#pragma unroll
        for (int i = 0; i < 4; ++i) {
            int f = i * 256 + tid;
            int mr = f >> 4, c4 = (f & 15) << 2;
            float4 v = *(const float4*)(xb + (size_t)(m0 + mr) * CT + c0 + c4);
            ushort4 u;
            u.x = f2bf(v.x); u.y = f2bf(v.y); u.z = f2bf(v.z); u.w = f2bf(v.w);
            *(ushort4*)&tile[mr][c4] = u;
        }
        __syncthreads();
        ushort* outp = Xt + (size_t)b * CT * NN;
#pragma unroll
        for (int i = 0; i < 4; ++i) {
            int f = i * 256 + tid;
            int n = f >> 4, m4 = (f & 15) << 2;
            int ctlin = c0 + n;                     // = c*36 + t
            int c = ctlin / 36, t = ctlin - 36 * c;
            int ctp = t * 16 + c;                   // t-major permuted row
            ushort4 u;
            u.x = tile[m4 + 0][n]; u.y = tile[m4 + 1][n];
            u.z = tile[m4 + 2][n]; u.w = tile[m4 + 3][n];
            *(ushort4*)(outp + (size_t)ctp * NN + m0 + m4) = u;
        }
    }
}

// -------- gemm1: rhs2[b][n][t][k*16+c] = sum_m At_k[n][m] * Xt[b][ct'][m] --------
// R6 (kept): k-FUSED tile (BM=64 n, all 3 k in one block, acc[3][2][3], B-frags
// shared across k) + stage-early ring-3 schedule + row-complete rhs2 epilogue.
// LDS: ring-3 x [A0|A1|A2 (64x64) | B (192x64)] bf16 = 3 x 48KB = 144 KB.
// Schedule: top-of-iter STAGE(kt+2) into slot (kt+2)%3 (holds tile kt-1, whose
// readers passed the end-of-iter-(kt-1) barrier -> legal); end-of-iter ONE
// {vmcnt(6); s_barrier} (tile kt+1 drained, kt+2's 6 loads in flight; never 0).
// Swizzle (rule #21 both-sides): LDS dest linear, source chunk c^(row&7),
// ds_read chunk (kp*4+quad)^(lrow&7).
// XCD: grid.x=48 (16 nt x 3 ctt), 48%8==0 -> XCD = x%8; A-sharers (same nt,
// 3 ctt) at x, x+16, x+32 -> same XCD L2.
__global__ __launch_bounds__(512) void gemm1(const ushort* __restrict__ At,
                                             const ushort* __restrict__ Xt,
                                             ushort* __restrict__ rhs2,
                                             int nsplit, int n_base, int rows) {
    __shared__ ushort lds[3 * 384 * 64];          // 147,456 B
    const int tid = threadIdx.x;
    const int b = blockIdx.y;
    const int ntiles = rows >> 6;
    const int nt = blockIdx.x % ntiles;
    const int ctt = blockIdx.x / ntiles;
    const int nloc0 = nt * 64;
    const int ct0 = ctt * 192;
    const int atrows = nsplit ? rows : NN;

    // staging: thread -> (row = tid>>3, chunk = tid&7), 16B slots; source chunk
    // pre-swizzled c ^ (row&7); LDS dest LINEAR.
    const int srow = tid >> 3, schunk = tid & 7;
    const int swz = schunk ^ (srow & 7);
    const ushort* a_src[3];
#pragma unroll
    for (int k = 0; k < 3; ++k)
        a_src[k] = At + ((size_t)(k * 16 + b) * atrows + nloc0 + srow) * NN + swz * 8;
    const ushort* b_src = Xt + (size_t)b * CT * NN + (size_t)(ct0 + srow) * NN + swz * 8;

    auto STAGE = [&](int kt, int p) {
        const int mk = kt * 64;
        ushort* base = lds + p * (384 * 64);
#pragma unroll
        for (int k = 0; k < 3; ++k)        // A_k: 64 rows x 8 chunks = 512 slots
            __builtin_amdgcn_global_load_lds(
                (const __attribute__((address_space(1))) void*)(a_src[k] + mk),
                (__attribute__((address_space(3))) void*)(base + k * 4096 + tid * 8), 16, 0, 0);
#pragma unroll
        for (int i = 0; i < 3; ++i)        // B: 192 rows x 8 chunks = 1536 slots
            __builtin_amdgcn_global_load_lds(
                (const __attribute__((address_space(1))) void*)(b_src + (size_t)i * 64 * NN + mk),
                (__attribute__((address_space(3))) void*)(base + 3 * 4096 + (tid + i * 512) * 8), 16, 0, 0);
    };

    const int w = tid >> 6, lane = tid & 63;
    const int wr = w >> 2, wc = w & 3;            // 2 x 4 wave grid: 32n x 48ct
    const int lrow = lane & 15, quad = lane >> 4;
    const int s3 = lrow & 7;
    f32x4 acc[3][2][3] = {};                      // [k][mi(n)][ni(ct)]

    STAGE(0, 0);                                  //  6 in flight
    STAGE(1, 1);                                  // 12 in flight
    asm volatile("s_waitcnt vmcnt(6)\n\ts_barrier" ::: "memory");   // tile 0 ready

    for (int kt = 0; kt < 16; ++kt) {
        if (kt + 2 < 16)
            STAGE(kt + 2, (kt + 2) % 3);          // issue EARLY: overlaps compute
        const ushort* bufA = lds + (kt % 3) * (384 * 64);
        const ushort* bufB = bufA + 3 * 4096;
#pragma unroll
        for (int kp = 0; kp < 2; ++kp) {
            const int koff = (((kp * 4 + quad) ^ s3) << 3);   // swizzled k-chunk
            bf16x8 af[3][2], bfr[3];
#pragma unroll
            for (int k = 0; k < 3; ++k)
#pragma unroll
                for (int mi = 0; mi < 2; ++mi)
                    af[k][mi] = *(const bf16x8*)&bufA[k * 4096 + (wr * 32 + mi * 16 + lrow) * 64 + koff];
#pragma unroll
            for (int ni = 0; ni < 3; ++ni)
                bfr[ni] = *(const bf16x8*)&bufB[(wc * 48 + ni * 16 + lrow) * 64 + koff];
            __builtin_amdgcn_s_setprio(1);
#pragma unroll
            for (int k = 0; k < 3; ++k)
#pragma unroll
                for (int mi = 0; mi < 2; ++mi)
#pragma unroll
                    for (int ni = 0; ni < 3; ++ni)
                        acc[k][mi][ni] = __builtin_amdgcn_mfma_f32_16x16x32_bf16(
                            af[k][mi], bfr[ni], acc[k][mi][ni], 0, 0, 0);
            __builtin_amdgcn_s_setprio(0);
        }
        // ONE sync point per iter: drain tile kt+1, keep kt+2's 6 in flight;
        // barrier doubles as "all waves done reading slot kt%3".
        if (kt + 2 < 16)
            asm volatile("s_waitcnt vmcnt(6)\n\ts_barrier" ::: "memory");
        else if (kt + 1 < 16)
            asm volatile("s_waitcnt vmcnt(0)\n\ts_barrier" ::: "memory");
        else
            asm volatile("s_barrier" ::: "memory");
    }

    // ---- epilogue: per-wave restage [n(32)][t(3)][kc(48)] (9216 B/wave), then
    // cooperative 16B stores of full 96B kc-rows (3 consecutive t = 288B bursts).
    ushort* sc = lds + w * 4608;
#pragma unroll
    for (int k = 0; k < 3; ++k)
#pragma unroll
        for (int mi = 0; mi < 2; ++mi)
#pragma unroll
            for (int ni = 0; ni < 3; ++ni)
#pragma unroll
                for (int r = 0; r < 4; ++r)
                    sc[((mi * 16 + quad * 4 + r) * 3 + ni) * 48 + k * 16 + lrow] =
                        f2bf(acc[k][mi][ni][r]);
    // wave-local LDS write->read: drain lgkm (no cross-wave sharing -> no barrier)
    asm volatile("s_waitcnt lgkmcnt(0)" ::: "memory");
    const int n_g0 = n_base + nloc0 + wr * 32;
    const int t_g0 = ctt * 12 + wc * 3;
#pragma unroll
    for (int i = 0; i < 9; ++i) {
        int seg = i * 64 + lane;          // 576 x 16B segments per wave
        int off = seg * 8;                // ushort offset in sc
        int nl = off / 144;               // 144 = 3t * 48kc
        int rem = off - nl * 144;
        int tl = rem / 48, kcol = rem - tl * 48;
        size_t g = (((size_t)b * NN + n_g0 + nl) * 36 + (t_g0 + tl)) * 48 + kcol;
        *(uint4*)(rhs2 + g) = *(const uint4*)&sc[off];
    }
}

// -------- apply_mfma2: out[b,n,o,t] = relu(sum_kc rhs2[b,n,t,kc] * theta[kc,o]) --------
// 16 bn per block (4 per wave, sequential). Stores LDS-staged for 1KB bursts.
__global__ __launch_bounds__(256) void apply_mfma2(const ushort* __restrict__ rhs2,
                                                   const float* __restrict__ theta,
                                                   float* __restrict__ out) {
    __shared__ ushort thT[64 * 72];       // [o][kc], kc in [48,64) zeroed
    __shared__ float ostage[4][64 * 36];  // per-wave staging, 9216 B each
    const int tid = threadIdx.x;
    for (int f = tid; f < 64 * 64; f += 256) {
        int o = f >> 6, kc = f & 63;
        thT[o * 72 + kc] = f2bf((kc < 48) ? theta[kc * 64 + o] : 0.f);
    }
    __syncthreads();
    const int w = tid >> 6, lane = tid & 63;
    const int lrow = lane & 15, quad = lane >> 4;

    bf16x8 a[4][2];
#pragma unroll
    for (int mi = 0; mi < 4; ++mi)
#pragma unroll
        for (int kc = 0; kc < 2; ++kc)
            a[mi][kc] = *(const bf16x8*)&thT[(mi * 16 + lrow) * 72 + kc * 32 + quad * 8];

    float* ost = &ostage[w][0];
    for (int j = 0; j < 4; ++j) {
        const int bn = blockIdx.x * 16 + w * 4 + j;
        const ushort* rrow = rhs2 + (size_t)bn * (36 * 48);
        f32x4 acc[4][3] = {};
#pragma unroll
        for (int ni = 0; ni < 3; ++ni)
#pragma unroll
            for (int kc = 0; kc < 2; ++kc) {
                // t-col >= 36 and kc-pad read in-bounds garbage (rhs2 is first in
                // ws, Xt follows): masked by zero theta rows / t<36 staging guard.
                bf16x8 bf = *(const bf16x8*)(rrow + (ni * 16 + lrow) * 48 + kc * 32 + quad * 8);
#pragma unroll
                for (int mi = 0; mi < 4; ++mi)
                    acc[mi][ni] = __builtin_amdgcn_mfma_f32_16x16x32_bf16(
                        a[mi][kc], bf, acc[mi][ni], 0, 0, 0);
            }
#pragma unroll
        for (int mi = 0; mi < 4; ++mi)
#pragma unroll
            for (int ni = 0; ni < 3; ++ni)
#pragma unroll
                for (int r = 0; r < 4; ++r) {
                    int t = ni * 16 + lrow;
                    if (t < 36)
                        ost[(mi * 16 + quad * 4 + r) * 36 + t] = fmaxf(acc[mi][ni][r], 0.f);
                }
        // wave-local LDS write->read across lanes: drain lgkm explicitly
        asm volatile("s_waitcnt lgkmcnt(0)" ::: "memory");
        float* ob = out + (size_t)bn * (COUT * TT);
#pragma unroll
        for (int q = 0; q < 9; ++q) {
            int f = q * 64 + lane;            // 576 float4 per row
            *(float4*)&ob[f * 4] = *(const float4*)&ost[f * 4];
        }
    }
}

// -------- naive fallback: zero workspace, fully fused --------
__global__ __launch_bounds__(256) void naive_fused(const float* __restrict__ x,
                                                   const float* __restrict__ sat,
                                                   const float* __restrict__ cheb,
                                                   const float* __restrict__ theta,
                                                   float* __restrict__ out) {
    __shared__ float wgt[3][1024];
    __shared__ float rs[3][576];
    const int tid = threadIdx.x;
    const int n = blockIdx.x, b = blockIdx.y;
    for (int f = tid; f < 3 * 1024; f += 256) {
        int k = f >> 10, m = f & 1023;
        wgt[k][m] = cheb[(size_t)k * NN * NN + (size_t)m * NN + n] *
                    sat[(size_t)b * NN * NN + (size_t)m * NN + n];
    }
    __syncthreads();
    float a0[3] = {}, a1[3] = {}, a2[3] = {};
    const float* xb = x + (size_t)b * NN * CT;
    for (int m = 0; m < 1024; ++m) {
        const float* xr = xb + (size_t)m * CT;
        float x0 = xr[tid];
        float x1 = xr[256 + tid];
        float x2 = (tid < 64) ? xr[512 + tid] : 0.f;
#pragma unroll
        for (int k = 0; k < 3; ++k) {
            float wm = wgt[k][m];
            a0[k] += wm * x0; a1[k] += wm * x1; a2[k] += wm * x2;
        }
    }
#pragma unroll
    for (int k = 0; k < 3; ++k) {
        rs[k][tid] = a0[k];
        rs[k][256 + tid] = a1[k];
        if (tid < 64) rs[k][512 + tid] = a2[k];
    }
    __syncthreads();
    const int o = tid >> 2, tg = tid & 3;
    float oa[9] = {};
    for (int kc = 0; kc < 48; ++kc) {
        int k = kc >> 4, c = kc & 15;
        float th = theta[kc * 64 + o];
        const float* rp = &rs[k][c * TT + tg * 9];
#pragma unroll
        for (int j = 0; j < 9; ++j) oa[j] += th * rp[j];
    }
    float* ob = out + ((size_t)b * NN + n) * (COUT * TT);
#pragma unroll
    for (int j = 0; j < 9; ++j)
        ob[o * TT + tg * 9 + j] = fmaxf(oa[j], 0.f);
}

extern "C" void kernel_launch(void* const* d_in, const int* in_sizes, int n_in,
                              void* d_out, int out_size, void* d_ws, size_t ws_size,
                              hipStream_t stream) {
    const float* x     = (const float*)d_in[0];   // [B,N,CIN,T]
    const float* sat   = (const float*)d_in[1];   // [B,N,N]
    const float* cheb  = (const float*)d_in[2];   // [K,N,N]
    const float* theta = (const float*)d_in[3];   // [K,CIN,COUT]
    float* out = (float*)d_out;

    const size_t RHS2 = (size_t)NB * NN * 36 * 48;   // 28.3M ushorts (56.6 MB)
    const size_t XT   = (size_t)NB * CT * NN;        //  9.4M (18.9 MB)
    const size_t ATF  = (size_t)KB * NN * NN;        // 50.3M (100.7 MB) full At
    const size_t ATNS = (size_t)KB * 512 * NN;       // 25.2M (50.3 MB) n-half chunk
    const size_t needA     = (RHS2 + XT + ATF) * 2;  // 176,160,768 B
    const size_t needSplit = (RHS2 + XT + ATNS) * 2; // 125,829,120 B

    // layout: rhs2 FIRST (apply's bounded over-reads land in Xt), then Xt, At
    ushort* rhs2 = (ushort*)d_ws;
    ushort* Xt   = rhs2 + RHS2;
    ushort* At   = Xt + XT;

    if (ws_size >= needA) {
        // merged preps: 768 prep_a blocks first (long pole), 2304 prep_x after
        prep_both<<<dim3(768 + 2304), 256, 0, stream>>>(cheb, sat, At, x, Xt, 0, 1024, 768);
        gemm1<<<dim3(48, NB), 512, 0, stream>>>(At, Xt, rhs2, 0, 0, 1024);
        apply_mfma2<<<dim3(NB * NN / 16), 256, 0, stream>>>(rhs2, theta, out);
    } else if (ws_size >= needSplit) {
        for (int half = 0; half < 2; ++half) {
            int nb = half * 512;
            // first half also carries prep_x (do once)
            int na = 384;
            int grid = na + (half == 0 ? 2304 : 0);
            prep_both<<<dim3(grid), 256, 0, stream>>>(cheb, sat, At, x, Xt, nb, 512, na);
            gemm1<<<dim3(24, NB), 512, 0, stream>>>(At, Xt, rhs2, 1, nb, 512);
        }
        apply_mfma2<<<dim3(NB * NN / 16), 256, 0, stream>>>(rhs2, theta, out);
    } else {
        naive_fused<<<dim3(NN, NB), 256, 0, stream>>>(x, sat, cheb, theta, out);
    }
}

// Round 8
// 369.774 us; speedup vs baseline: 1.3371x; 1.0103x over previous
//
#include <hip/hip_runtime.h>
#include <hip/hip_bf16.h>

// Problem constants
#define NB 16      // batch
#define NN 1024    // nodes
#define CIN 16
#define TT 36
#define KK 3
#define COUT 64
#define CT 576     // CIN*TT
#define KB 48      // KK*NB

typedef __attribute__((ext_vector_type(8))) short bf16x8;
typedef __attribute__((ext_vector_type(4))) float f32x4;

__device__ __forceinline__ unsigned short f2bf(float f) {
    union { float f; unsigned int u; } v; v.f = f;
    unsigned int r = v.u + 0x7FFF + ((v.u >> 16) & 1);
    return (unsigned short)(r >> 16);
}

// -------- prep_both: fused prep_a + prep_x (independent -> one dispatch) --------
// Blocks [0, na): prep_a body (k-trio XCD residue preserved).
// Blocks [na, ...): prep_x body.
__global__ __launch_bounds__(256) void prep_both(const float* __restrict__ cheb,
                                                 const float* __restrict__ sat,
                                                 ushort* __restrict__ At,
                                                 const float* __restrict__ x,
                                                 ushort* __restrict__ Xt,
                                                 int n_base, int rows, int na_blocks) {
    __shared__ ushort tile[64][68];
    const int tid = threadIdx.x;
    const int bid = blockIdx.x;

    if (bid < na_blocks) {
        // ---------------- prep_a: At[l][n-n_base][m] = bf16(cheb*sat) ----------------
        const int ntiles = rows >> 6;
        const int per_k = ntiles * 16;
        const int k = bid / per_k;
        const int bx = bid - k * per_k;
        const int n0 = n_base + (bx % ntiles) * 64;
        const int m0 = (bx / ntiles) * 64;

        size_t goff[4];
        float4 cv[4], sv[4];
#pragma unroll
        for (int i = 0; i < 4; ++i) {
            int f = i * 256 + tid;
            goff[i] = (size_t)(m0 + (f >> 4)) * NN + n0 + ((f & 15) << 2);
            cv[i] = *(const float4*)(cheb + (size_t)k * NN * NN + goff[i]);
            sv[i] = *(const float4*)(sat + goff[i]);      // b = 0
        }
        for (int b = 0; b < 16; ++b) {
#pragma unroll
            for (int i = 0; i < 4; ++i) {
                int f = i * 256 + tid;
                ushort4 u;
                u.x = f2bf(cv[i].x * sv[i].x); u.y = f2bf(cv[i].y * sv[i].y);
                u.z = f2bf(cv[i].z * sv[i].z); u.w = f2bf(cv[i].w * sv[i].w);
                *(ushort4*)&tile[f >> 4][(f & 15) << 2] = u;
            }
            if (b < 15) {
                const float* sa = sat + (size_t)(b + 1) * NN * NN;
#pragma unroll
                for (int i = 0; i < 4; ++i) sv[i] = *(const float4*)(sa + goff[i]);
            }
            __syncthreads();
            ushort* outp = At + (size_t)(k * 16 + b) * rows * NN;
#pragma unroll
            for (int i = 0; i < 4; ++i) {
                int f = i * 256 + tid;
                int n = f >> 4, m4 = (f & 15) << 2;
                ushort4 u;
                u.x = tile[m4 + 0][n]; u.y = tile[m4 + 1][n];
                u.z = tile[m4 + 2][n]; u.w = tile[m4 + 3][n];
                *(ushort4*)(outp + (size_t)(n0 - n_base + n) * NN + m0 + m4) = u;
            }
            __syncthreads();   // tile reused next b-iteration
        }
    } else {
        // ---------------- prep_x: Xt[b][t*16+c][m] = bf16(x[b][m][c][t]) ------------
        const int f0 = bid - na_blocks;
        const int b = f0 / 144;
        const int bx = f0 - b * 144;
        const int m0 = (bx & 15) * 64;
        const int c0 = (bx >> 4) * 64;
        const float* xb = x + (size_t)b * NN * CT;
#pragma unroll
        for (int i = 0; i < 4; ++i) {
            int f = i * 256 + tid;
            int mr = f >> 4, c4 = (f & 15) << 2;
            float4 v = *(const float4*)(xb + (size_t)(m0 + mr) * CT + c0 + c4);
            ushort4 u;
            u.x = f2bf(v.x); u.y = f2bf(v.y); u.z = f2bf(v.z); u.w = f2bf(v.w);
            *(ushort4*)&tile[mr][c4] = u;
        }
        __syncthreads();
        ushort* outp = Xt + (size_t)b * CT * NN;
#pragma unroll
        for (int i = 0; i < 4; ++i) {
            int f = i * 256 + tid;
            int n = f >> 4, m4 = (f & 15) << 2;
            int ctlin = c0 + n;                     // = c*36 + t
            int c = ctlin / 36, t = ctlin - 36 * c;
            int ctp = t * 16 + c;                   // t-major permuted row
            ushort4 u;
            u.x = tile[m4 + 0][n]; u.y = tile[m4 + 1][n];
            u.z = tile[m4 + 2][n]; u.w = tile[m4 + 3][n];
            *(ushort4*)(outp + (size_t)ctp * NN + m0 + m4) = u;
        }
    }
}

// -------- gemm1: rhs2[b][n][t][k*16+c] = sum_m At_k[n][m] * Xt[b][ct'][m] --------
// R8: 2-BLOCKS/CU variant. R7's 147KB LDS forced 1 block/CU, so every
// vmcnt+barrier stalled ALL resident waves (no co-resident block to overlap --
// the m233 structural stall; m97/m114 show >=2 blocks/CU absorbs barrier drains
// via inter-block wave overlap). BK 64->32: ring-3 x [A 3x64x32 | B 192x32] bf16
// = 3 x 24KB = 72KB LDS -> 2 blocks/CU (16 waves/CU), enforced by
// __launch_bounds__(512,4) (4 waves/EU; VGPR cap 128, we use ~88).
// Same k-fused tile (BM=64, acc[3][2][3]), stage-early ring-3, counted vmcnt:
// 3 loads/thread/stage -> vmcnt(3) drains tile kt+1, keeps kt+2 in flight.
// Swizzle (both-sides, 64B rows -> 4 chunks of 16B): stored chunk c holds global
// chunk c ^ ((row>>1)&3); ds_read chunk = quad ^ ((row>>1)&3); fragment rows are
// multiples of 16 + lrow so read XOR = (lrow>>1)&3. Unswizzle check: read returns
// global chunk quad (= MFMA k-offset quad*8) for every row.
// XCD: grid.x=48 (16 nt x 3 ctt), 48%8==0 -> XCD = x%8; A-sharers at x,x+16,x+32.
__global__ __launch_bounds__(512, 4) void gemm1(const ushort* __restrict__ At,
                                                const ushort* __restrict__ Xt,
                                                ushort* __restrict__ rhs2,
                                                int nsplit, int n_base, int rows) {
    __shared__ ushort lds[3 * 384 * 32];          // 73,728 B (3 x 12288 ushorts)
    const int tid = threadIdx.x;
    const int b = blockIdx.y;
    const int ntiles = rows >> 6;
    const int nt = blockIdx.x % ntiles;
    const int ctt = blockIdx.x / ntiles;
    const int nloc0 = nt * 64;
    const int ct0 = ctt * 192;
    const int atrows = nsplit ? rows : NN;

    const ushort* AtB = At + (size_t)b * atrows * NN;              // k stride 16*atrows*NN
    const ushort* XtB = Xt + (size_t)b * CT * NN + (size_t)ct0 * NN;

    // slot s = i*512 + tid (i=0..2), 16B slots, LDS dest LINEAR (s*8 ushorts).
    //   s < 768:  A slot: k = s>>8, row = (s>>2)&63, chunk = s&3
    //   s >= 768: B slot: row = (s-768)>>2, chunk = s&3
    // global source chunk pre-swizzled: c ^ ((row>>1)&3).
    size_t srcoff[3];                             // ushort offsets (mk added later)
#pragma unroll
    for (int i = 0; i < 3; ++i) {
        int s = i * 512 + tid;
        if (s < 768) {
            int k = s >> 8, rr = (s >> 2) & 63, cc = s & 3;
            int cs = cc ^ ((rr >> 1) & 3);
            srcoff[i] = (size_t)(k * 16) * atrows * NN + (size_t)(nloc0 + rr) * NN + cs * 8;
        } else {
            int sb = s - 768;
            int rr = sb >> 2, cc = sb & 3;
            int cs = cc ^ ((rr >> 1) & 3);
            srcoff[i] = (size_t)rr * NN + cs * 8;  // relative to XtB
        }
    }
    const bool isA0 = (tid < 512);                // i=0 always A
    // i=1: tid<256 -> A, else B; i=2 always B
    auto SRC = [&](int i, int mk) -> const ushort* {
        int s = i * 512 + tid;
        const ushort* base = (s < 768) ? AtB : XtB;
        return base + srcoff[i] + mk;
    };

    auto STAGE = [&](int kt, int p) {
        const int mk = kt * 32;
        ushort* base = lds + p * 12288;
#pragma unroll
        for (int i = 0; i < 3; ++i)
            __builtin_amdgcn_global_load_lds(
                (const __attribute__((address_space(1))) void*)SRC(i, mk),
                (__attribute__((address_space(3))) void*)(base + (tid + i * 512) * 8), 16, 0, 0);
    };

    const int w = tid >> 6, lane = tid & 63;
    const int wr = w >> 2, wc = w & 3;            // 2 x 4 wave grid: 32n x 48ct
    const int lrow = lane & 15, quad = lane >> 4;
    const int koff = ((quad ^ ((lrow >> 1) & 3)) << 3);   // swizzled chunk, ushorts
    f32x4 acc[3][2][3] = {};                      // [k][mi(n)][ni(ct)]

    STAGE(0, 0);                                  // 3 in flight
    STAGE(1, 1);                                  // 6 in flight
    asm volatile("s_waitcnt vmcnt(3)\n\ts_barrier" ::: "memory");   // tile 0 ready

    for (int kt = 0; kt < 32; ++kt) {
        if (kt + 2 < 32)
            STAGE(kt + 2, (kt + 2) % 3);          // issue EARLY: overlaps compute
        const ushort* buf = lds + (kt % 3) * 12288;
        bf16x8 af[3][2], bfr[3];
#pragma unroll
        for (int k = 0; k < 3; ++k)
#pragma unroll
            for (int mi = 0; mi < 2; ++mi)
                af[k][mi] = *(const bf16x8*)&buf[k * 2048 + (wr * 32 + mi * 16 + lrow) * 32 + koff];
#pragma unroll
        for (int ni = 0; ni < 3; ++ni)
            bfr[ni] = *(const bf16x8*)&buf[6144 + (wc * 48 + ni * 16 + lrow) * 32 + koff];
        __builtin_amdgcn_s_setprio(1);
#pragma unroll
        for (int k = 0; k < 3; ++k)
#pragma unroll
            for (int mi = 0; mi < 2; ++mi)
#pragma unroll
                for (int ni = 0; ni < 3; ++ni)
                    acc[k][mi][ni] = __builtin_amdgcn_mfma_f32_16x16x32_bf16(
                        af[k][mi], bfr[ni], acc[k][mi][ni], 0, 0, 0);
        __builtin_amdgcn_s_setprio(0);
        // ONE sync point per iter: drain tile kt+1 (3 oldest), keep kt+2's 3 in
        // flight; barrier doubles as "all waves done reading slot kt%3".
        if (kt + 2 < 32)
            asm volatile("s_waitcnt vmcnt(3)\n\ts_barrier" ::: "memory");
        else if (kt + 1 < 32)
            asm volatile("s_waitcnt vmcnt(0)\n\ts_barrier" ::: "memory");
        else
            asm volatile("s_barrier" ::: "memory");
    }

    // ---- epilogue: per-wave restage [n(32)][t(3)][kc(48)] (9216 B/wave), then
    // cooperative 16B stores of full 96B kc-rows (3 consecutive t = 288B bursts).
    ushort* sc = lds + w * 4608;                  // 8 x 4608 = 36,864 <= 73,728
#pragma unroll
    for (int k = 0; k < 3; ++k)
#pragma unroll
        for (int mi = 0; mi < 2; ++mi)
#pragma unroll
            for (int ni = 0; ni < 3; ++ni)
#pragma unroll
                for (int r = 0; r < 4; ++r)
                    sc[((mi * 16 + quad * 4 + r) * 3 + ni) * 48 + k * 16 + lrow] =
                        f2bf(acc[k][mi][ni][r]);
    // wave-local LDS write->read: drain lgkm (no cross-wave sharing -> no barrier)
    asm volatile("s_waitcnt lgkmcnt(0)" ::: "memory");
    const int n_g0 = n_base + nloc0 + wr * 32;
    const int t_g0 = ctt * 12 + wc * 3;
#pragma unroll
    for (int i = 0; i < 9; ++i) {
        int seg = i * 64 + lane;          // 576 x 16B segments per wave
        int off = seg * 8;                // ushort offset in sc
        int nl = off / 144;               // 144 = 3t * 48kc
        int rem = off - nl * 144;
        int tl = rem / 48, kcol = rem - tl * 48;
        size_t g = (((size_t)b * NN + n_g0 + nl) * 36 + (t_g0 + tl)) * 48 + kcol;
        *(uint4*)(rhs2 + g) = *(const uint4*)&sc[off];
    }
}

// -------- apply_mfma2: out[b,n,o,t] = relu(sum_kc rhs2[b,n,t,kc] * theta[kc,o]) --------
// 16 bn per block (4 per wave, sequential). Stores LDS-staged for 1KB bursts.
__global__ __launch_bounds__(256) void apply_mfma2(const ushort* __restrict__ rhs2,
                                                   const float* __restrict__ theta,
                                                   float* __restrict__ out) {
    __shared__ ushort thT[64 * 72];       // [o][kc], kc in [48,64) zeroed
    __shared__ float ostage[4][64 * 36];  // per-wave staging, 9216 B each
    const int tid = threadIdx.x;
    for (int f = tid; f < 64 * 64; f += 256) {
        int o = f >> 6, kc = f & 63;
        thT[o * 72 + kc] = f2bf((kc < 48) ? theta[kc * 64 + o] : 0.f);
    }
    __syncthreads();
    const int w = tid >> 6, lane = tid & 63;
    const int lrow = lane & 15, quad = lane >> 4;

    bf16x8 a[4][2];
#pragma unroll
    for (int mi = 0; mi < 4; ++mi)
#pragma unroll
        for (int kc = 0; kc < 2; ++kc)
            a[mi][kc] = *(const bf16x8*)&thT[(mi * 16 + lrow) * 72 + kc * 32 + quad * 8];

    float* ost = &ostage[w][0];
    for (int j = 0; j < 4; ++j) {
        const int bn = blockIdx.x * 16 + w * 4 + j;
        const ushort* rrow = rhs2 + (size_t)bn * (36 * 48);
        f32x4 acc[4][3] = {};
#pragma unroll
        for (int ni = 0; ni < 3; ++ni)
#pragma unroll
            for (int kc = 0; kc < 2; ++kc) {
                // t-col >= 36 and kc-pad read in-bounds garbage (rhs2 is first in
                // ws, Xt follows): masked by zero theta rows / t<36 staging guard.
                bf16x8 bf = *(const bf16x8*)(rrow + (ni * 16 + lrow) * 48 + kc * 32 + quad * 8);
#pragma unroll
                for (int mi = 0; mi < 4; ++mi)
                    acc[mi][ni] = __builtin_amdgcn_mfma_f32_16x16x32_bf16(
                        a[mi][kc], bf, acc[mi][ni], 0, 0, 0);
            }
#pragma unroll
        for (int mi = 0; mi < 4; ++mi)
#pragma unroll
            for (int ni = 0; ni < 3; ++ni)
#pragma unroll
                for (int r = 0; r < 4; ++r) {
                    int t = ni * 16 + lrow;
                    if (t < 36)
                        ost[(mi * 16 + quad * 4 + r) * 36 + t] = fmaxf(acc[mi][ni][r], 0.f);
                }
        // wave-local LDS write->read across lanes: drain lgkm explicitly
        asm volatile("s_waitcnt lgkmcnt(0)" ::: "memory");
        float* ob = out + (size_t)bn * (COUT * TT);
#pragma unroll
        for (int q = 0; q < 9; ++q) {
            int f = q * 64 + lane;            // 576 float4 per row
            *(float4*)&ob[f * 4] = *(const float4*)&ost[f * 4];
        }
    }
}

// -------- naive fallback: zero workspace, fully fused --------
__global__ __launch_bounds__(256) void naive_fused(const float* __restrict__ x,
                                                   const float* __restrict__ sat,
                                                   const float* __restrict__ cheb,
                                                   const float* __restrict__ theta,
                                                   float* __restrict__ out) {
    __shared__ float wgt[3][1024];
    __shared__ float rs[3][576];
    const int tid = threadIdx.x;
    const int n = blockIdx.x, b = blockIdx.y;
    for (int f = tid; f < 3 * 1024; f += 256) {
        int k = f >> 10, m = f & 1023;
        wgt[k][m] = cheb[(size_t)k * NN * NN + (size_t)m * NN + n] *
                    sat[(size_t)b * NN * NN + (size_t)m * NN + n];
    }
    __syncthreads();
    float a0[3] = {}, a1[3] = {}, a2[3] = {};
    const float* xb = x + (size_t)b * NN * CT;
    for (int m = 0; m < 1024; ++m) {
        const float* xr = xb + (size_t)m * CT;
        float x0 = xr[tid];
        float x1 = xr[256 + tid];
        float x2 = (tid < 64) ? xr[512 + tid] : 0.f;
#pragma unroll
        for (int k = 0; k < 3; ++k) {
            float wm = wgt[k][m];
            a0[k] += wm * x0; a1[k] += wm * x1; a2[k] += wm * x2;
        }
    }
#pragma unroll
    for (int k = 0; k < 3; ++k) {
        rs[k][tid] = a0[k];
        rs[k][256 + tid] = a1[k];
        if (tid < 64) rs[k][512 + tid] = a2[k];
    }
    __syncthreads();
    const int o = tid >> 2, tg = tid & 3;
    float oa[9] = {};
    for (int kc = 0; kc < 48; ++kc) {
        int k = kc >> 4, c = kc & 15;
        float th = theta[kc * 64 + o];
        const float* rp = &rs[k][c * TT + tg * 9];
#pragma unroll
        for (int j = 0; j < 9; ++j) oa[j] += th * rp[j];
    }
    float* ob = out + ((size_t)b * NN + n) * (COUT * TT);
#pragma unroll
    for (int j = 0; j < 9; ++j)
        ob[o * TT + tg * 9 + j] = fmaxf(oa[j], 0.f);
}

extern "C" void kernel_launch(void* const* d_in, const int* in_sizes, int n_in,
                              void* d_out, int out_size, void* d_ws, size_t ws_size,
                              hipStream_t stream) {
    const float* x     = (const float*)d_in[0];   // [B,N,CIN,T]
    const float* sat   = (const float*)d_in[1];   // [B,N,N]
    const float* cheb  = (const float*)d_in[2];   // [K,N,N]
    const float* theta = (const float*)d_in[3];   // [K,CIN,COUT]
    float* out = (float*)d_out;

    const size_t RHS2 = (size_t)NB * NN * 36 * 48;   // 28.3M ushorts (56.6 MB)
    const size_t XT   = (size_t)NB * CT * NN;        //  9.4M (18.9 MB)
    const size_t ATF  = (size_t)KB * NN * NN;        // 50.3M (100.7 MB) full At
    const size_t ATNS = (size_t)KB * 512 * NN;       // 25.2M (50.3 MB) n-half chunk
    const size_t needA     = (RHS2 + XT + ATF) * 2;  // 176,160,768 B
    const size_t needSplit = (RHS2 + XT + ATNS) * 2; // 125,829,120 B

    // layout: rhs2 FIRST (apply's bounded over-reads land in Xt), then Xt, At
    ushort* rhs2 = (ushort*)d_ws;
    ushort* Xt   = rhs2 + RHS2;
    ushort* At   = Xt + XT;

    if (ws_size >= needA) {
        // merged preps: 768 prep_a blocks first (long pole), 2304 prep_x after
        prep_both<<<dim3(768 + 2304), 256, 0, stream>>>(cheb, sat, At, x, Xt, 0, 1024, 768);
        gemm1<<<dim3(48, NB), 512, 0, stream>>>(At, Xt, rhs2, 0, 0, 1024);
        apply_mfma2<<<dim3(NB * NN / 16), 256, 0, stream>>>(rhs2, theta, out);
    } else if (ws_size >= needSplit) {
        for (int half = 0; half < 2; ++half) {
            int nb = half * 512;
            // first half also carries prep_x (do once)
            int na = 384;
            int grid = na + (half == 0 ? 2304 : 0);
            prep_both<<<dim3(grid), 256, 0, stream>>>(cheb, sat, At, x, Xt, nb, 512, na);
            gemm1<<<dim3(24, NB), 512, 0, stream>>>(At, Xt, rhs2, 1, nb, 512);
        }
        apply_mfma2<<<dim3(NB * NN / 16), 256, 0, stream>>>(rhs2, theta, out);
    } else {
        naive_fused<<<dim3(NN, NB), 256, 0, stream>>>(x, sat, cheb, theta, out);
    }
}